// Round 1
// baseline (1520.606 us; speedup 1.0000x reference)
//
#include <hip/hip_runtime.h>
#include <hip/hip_bf16.h>

// GRUModel: B=4096, T=256, D=5, H=64, 2 stacked GRU layers + FC(64->1).
// Strategy: fused single kernel. Lane j owns hidden unit j (gates j, 64+j,
// 128+j). One wave processes 4 batch rows; block = 4 waves = 16 rows;
// 256 blocks = 1 block/CU (152KB LDS). No __syncthreads in the t-loop:
// h-state rows are wave-private, wave-lockstep + compiler lgkmcnt waits
// give in-wave LDS ordering.

#define T_SZ 256
#define D_IN 5
#define H_SZ 64
#define RPW 4   // rows per wave
#define RPB 16  // rows per block (4 waves)

__device__ __forceinline__ float sigmoid_f(float v) {
    float e = __expf(-v);
    return __builtin_amdgcn_rcpf(1.0f + e);
}
__device__ __forceinline__ float tanh_f(float v) {
    float e = __expf(-2.0f * v);
    return (1.0f - e) * __builtin_amdgcn_rcpf(1.0f + e);
}

#define DOT4(acc, w4, h4)                    \
    acc = fmaf((w4).x, (h4).x, acc);         \
    acc = fmaf((w4).y, (h4).y, acc);         \
    acc = fmaf((w4).z, (h4).z, acc);         \
    acc = fmaf((w4).w, (h4).w, acc);

__global__ __launch_bounds__(256, 1)
void gru2_fused(const float* __restrict__ x,
                const float* __restrict__ w_ih0, const float* __restrict__ w_hh0,
                const float* __restrict__ b_ih0, const float* __restrict__ b_hh0,
                const float* __restrict__ w_ih1, const float* __restrict__ w_hh1,
                const float* __restrict__ b_ih1, const float* __restrict__ b_hh1,
                const float* __restrict__ fc_w, const float* __restrict__ fc_b,
                float* __restrict__ out)
{
    // weight layouts: [k4][q][lane][ki] so lanes read float4 at 16B stride
    __shared__ __align__(16) float wA[16][3][64][4];  // w_hh0
    __shared__ __align__(16) float wB[16][3][64][4];  // w_ih1
    __shared__ __align__(16) float wC[16][3][64][4];  // w_hh1
    __shared__ __align__(16) float h0s[RPB][H_SZ];
    __shared__ __align__(16) float h1s[RPB][H_SZ];

    const int tid = threadIdx.x;

    // repack the three 192x64 matrices (coalesced global reads, once)
    for (int idx = tid; idx < 192 * 64; idx += 256) {
        int g = idx >> 6, k = idx & 63;
        int k4 = k >> 2, ki = k & 3, q = g >> 6, ln = g & 63;
        wA[k4][q][ln][ki] = w_hh0[idx];
        wB[k4][q][ln][ki] = w_ih1[idx];
        wC[k4][q][ln][ki] = w_hh1[idx];
    }
    for (int idx = tid; idx < RPB * H_SZ; idx += 256) {
        ((float*)h0s)[idx] = 0.0f;
        ((float*)h1s)[idx] = 0.0f;
    }
    __syncthreads();

    const int lane = tid & 63;
    const int wave = tid >> 6;
    const int rl0  = wave * RPW;
    // readfirstlane -> provably wave-uniform -> scalar loads for x
    const int rowBase = __builtin_amdgcn_readfirstlane(blockIdx.x * RPB + rl0);

    // per-lane persistent weights/biases (gate rows lane, 64+lane, 128+lane)
    float wi0r[D_IN], wi0z[D_IN], wi0n[D_IN];
#pragma unroll
    for (int d = 0; d < D_IN; ++d) {
        wi0r[d] = w_ih0[(0 * 64 + lane) * D_IN + d];
        wi0z[d] = w_ih0[(1 * 64 + lane) * D_IN + d];
        wi0n[d] = w_ih0[(2 * 64 + lane) * D_IN + d];
    }
    const float bR0  = b_ih0[lane] + b_hh0[lane];
    const float bZ0  = b_ih0[64 + lane] + b_hh0[64 + lane];
    const float bXN0 = b_ih0[128 + lane];
    const float bHN0 = b_hh0[128 + lane];
    const float bR1  = b_ih1[lane] + b_hh1[lane];
    const float bZ1  = b_ih1[64 + lane] + b_hh1[64 + lane];
    const float bXN1 = b_ih1[128 + lane];
    const float bHN1 = b_hh1[128 + lane];
    const float fcw  = fc_w[lane];

    float h0r[RPW] = {0.f, 0.f, 0.f, 0.f};  // own element h0[row][lane]
    float h1r[RPW] = {0.f, 0.f, 0.f, 0.f};

    for (int t = 0; t < T_SZ; ++t) {
        // ================= Layer 0 =================
        float aR[RPW], aZ[RPW], aXN[RPW], aHN[RPW];
#pragma unroll
        for (int rr = 0; rr < RPW; ++rr) {
            const float* xp = x + ((size_t)(rowBase + rr) * T_SZ + t) * D_IN;
            float x0 = xp[0], x1 = xp[1], x2 = xp[2], x3 = xp[3], x4 = xp[4];
            aR[rr]  = fmaf(wi0r[4], x4, fmaf(wi0r[3], x3, fmaf(wi0r[2], x2,
                      fmaf(wi0r[1], x1, fmaf(wi0r[0], x0, bR0)))));
            aZ[rr]  = fmaf(wi0z[4], x4, fmaf(wi0z[3], x3, fmaf(wi0z[2], x2,
                      fmaf(wi0z[1], x1, fmaf(wi0z[0], x0, bZ0)))));
            aXN[rr] = fmaf(wi0n[4], x4, fmaf(wi0n[3], x3, fmaf(wi0n[2], x2,
                      fmaf(wi0n[1], x1, fmaf(wi0n[0], x0, bXN0)))));
            aHN[rr] = bHN0;
        }
#pragma unroll
        for (int k4 = 0; k4 < 16; ++k4) {
            const float4 wr = *(const float4*)wA[k4][0][lane];
            const float4 wz = *(const float4*)wA[k4][1][lane];
            const float4 wn = *(const float4*)wA[k4][2][lane];
#pragma unroll
            for (int rr = 0; rr < RPW; ++rr) {
                const float4 hv = *(const float4*)&h0s[rl0 + rr][k4 * 4];
                DOT4(aR[rr],  wr, hv);
                DOT4(aZ[rr],  wz, hv);
                DOT4(aHN[rr], wn, hv);
            }
        }
#pragma unroll
        for (int rr = 0; rr < RPW; ++rr) {
            float r = sigmoid_f(aR[rr]);
            float z = sigmoid_f(aZ[rr]);
            float n = tanh_f(fmaf(r, aHN[rr], aXN[rr]));
            float hv = (1.0f - z) * n + z * h0r[rr];
            h0r[rr] = hv;
            h0s[rl0 + rr][lane] = hv;
        }
        // ================= Layer 1 =================
        float cR[RPW], cZ[RPW], cXN[RPW], cHN[RPW];
#pragma unroll
        for (int rr = 0; rr < RPW; ++rr) {
            cR[rr] = bR1; cZ[rr] = bZ1; cXN[rr] = bXN1; cHN[rr] = bHN1;
        }
#pragma unroll
        for (int k4 = 0; k4 < 16; ++k4) {
            const float4 xr4 = *(const float4*)wB[k4][0][lane];
            const float4 xz4 = *(const float4*)wB[k4][1][lane];
            const float4 xn4 = *(const float4*)wB[k4][2][lane];
            const float4 hr4 = *(const float4*)wC[k4][0][lane];
            const float4 hz4 = *(const float4*)wC[k4][1][lane];
            const float4 hn4 = *(const float4*)wC[k4][2][lane];
#pragma unroll
            for (int rr = 0; rr < RPW; ++rr) {
                const float4 u = *(const float4*)&h0s[rl0 + rr][k4 * 4];
                const float4 v = *(const float4*)&h1s[rl0 + rr][k4 * 4];
                DOT4(cR[rr],  xr4, u);
                DOT4(cR[rr],  hr4, v);
                DOT4(cZ[rr],  xz4, u);
                DOT4(cZ[rr],  hz4, v);
                DOT4(cXN[rr], xn4, u);
                DOT4(cHN[rr], hn4, v);
            }
        }
#pragma unroll
        for (int rr = 0; rr < RPW; ++rr) {
            float r = sigmoid_f(cR[rr]);
            float z = sigmoid_f(cZ[rr]);
            float n = tanh_f(fmaf(r, cHN[rr], cXN[rr]));
            float hv = (1.0f - z) * n + z * h1r[rr];
            h1r[rr] = hv;
            h1s[rl0 + rr][lane] = hv;
        }
    }

    // ============ FC epilogue: out[row] = h1 . fc_w + fc_b ============
    const float fcb = fc_b[0];
#pragma unroll
    for (int rr = 0; rr < RPW; ++rr) {
        float v = fcw * h1r[rr];
#pragma unroll
        for (int off = 32; off > 0; off >>= 1) v += __shfl_xor(v, off, 64);
        if (lane == 0) out[rowBase + rr] = v + fcb;
    }
}

extern "C" void kernel_launch(void* const* d_in, const int* in_sizes, int n_in,
                              void* d_out, int out_size, void* d_ws, size_t ws_size,
                              hipStream_t stream) {
    const float* x     = (const float*)d_in[0];
    const float* w_ih0 = (const float*)d_in[1];
    const float* w_hh0 = (const float*)d_in[2];
    const float* b_ih0 = (const float*)d_in[3];
    const float* b_hh0 = (const float*)d_in[4];
    const float* w_ih1 = (const float*)d_in[5];
    const float* w_hh1 = (const float*)d_in[6];
    const float* b_ih1 = (const float*)d_in[7];
    const float* b_hh1 = (const float*)d_in[8];
    const float* fc_w  = (const float*)d_in[9];
    const float* fc_b  = (const float*)d_in[10];
    float* out = (float*)d_out;

    dim3 grid(4096 / RPB);   // 256 blocks -> 1 per CU
    dim3 block(256);         // 4 waves
    gru2_fused<<<grid, block, 0, stream>>>(x, w_ih0, w_hh0, b_ih0, b_hh0,
                                           w_ih1, w_hh1, b_ih1, b_hh1,
                                           fc_w, fc_b, out);
}

// Round 3
// 422.891 us; speedup vs baseline: 3.5957x; 3.5957x over previous
//
#include <hip/hip_runtime.h>
#include <hip/hip_bf16.h>

// GRU2 + FC, MFMA version.
// Block = 16 batch rows, 4 waves. Wave w owns gate-unit chunk [16w,16w+16).
// Lane l: unit u = 16w + (l&15); D-rows (batch) 4*(l>>4)+reg (verified m89
// C/D layout: col=lane&15, row=(lane>>4)*4+reg).
// A-frag (h, 16x64): row = lane&15, k = kk*32 + 8*(lane>>4) + j (AMD lab-notes
// mapping for 16x16x32).
// fp32 accuracy via bf16 hi/lo split: acc += Ahi*Bhi + Alo*Bhi + Ahi*Blo.
// Weights converted once into per-lane register B-fragments (no LDS stream).

typedef __attribute__((ext_vector_type(8))) __bf16 bf16x8;
typedef __attribute__((ext_vector_type(4))) float f32x4;

#define MFMA16(a, b, c) __builtin_amdgcn_mfma_f32_16x16x32_bf16(a, b, c, 0, 0, 0)

#define T_SZ 256
#define XROW 1284  // 1280 + 4 pad (1280%32==0 -> 4-way bank conflict unpadded)
#define HROW 68    // 64 + 4 pad

__device__ __forceinline__ float sigmoid_f(float v) {
    float e = __expf(-v);
    return __builtin_amdgcn_rcpf(1.0f + e);
}
__device__ __forceinline__ float tanh_f(float v) {
    float e = __expf(-2.0f * v);
    return (1.0f - e) * __builtin_amdgcn_rcpf(1.0f + e);
}

__device__ __forceinline__ void cvt_hilo8(const float* v, bf16x8& hi, bf16x8& lo) {
#pragma unroll
    for (int j = 0; j < 8; ++j) {
        __bf16 h = (__bf16)v[j];
        hi[j] = h;
        lo[j] = (__bf16)(v[j] - (float)h);   // exact residual, then RNE
    }
}

__device__ __forceinline__ void load_wfrag(const float* __restrict__ W, int grow,
                                           int kbase, bf16x8& hi, bf16x8& lo) {
    float v[8];
#pragma unroll
    for (int j = 0; j < 8; ++j) v[j] = W[grow * 64 + kbase + j];
    cvt_hilo8(v, hi, lo);
}

__device__ __forceinline__ void load_afrag(const float* row, int kbase,
                                           bf16x8& hi, bf16x8& lo) {
    float4 a = *(const float4*)(row + kbase);
    float4 b = *(const float4*)(row + kbase + 4);
    float v[8] = {a.x, a.y, a.z, a.w, b.x, b.y, b.z, b.w};
    cvt_hilo8(v, hi, lo);
}

__global__ __launch_bounds__(256, 1)
void gru2_mfma(const float* __restrict__ x,
               const float* __restrict__ w_ih0, const float* __restrict__ w_hh0,
               const float* __restrict__ b_ih0, const float* __restrict__ b_hh0,
               const float* __restrict__ w_ih1, const float* __restrict__ w_hh1,
               const float* __restrict__ b_ih1, const float* __restrict__ b_hh1,
               const float* __restrict__ fc_w, const float* __restrict__ fc_b,
               float* __restrict__ out)
{
    __shared__ __align__(16) float xs[16][XROW];      // ~82 KB
    __shared__ __align__(16) float h0s[2][16][HROW];  // 8.7 KB
    __shared__ __align__(16) float h1s[2][16][HROW];  // 8.7 KB

    const int tid = threadIdx.x;
    const int lane = tid & 63;
    const int wave = tid >> 6;
    const int u    = lane & 15;       // unit offset in wave's chunk / A-row
    const int kq   = lane >> 4;       // k-quadrant / D row-group
    const int ug   = wave * 16 + u;   // global gate-unit 0..63
    const int rbase = 4 * kq;         // lane's batch-row base (within block)

    // ---- stage x slice (contiguous per block), padded rows ----
    {
        const float4* src = (const float4*)(x + (size_t)blockIdx.x * 16 * 1280);
#pragma unroll 1
        for (int r = 0; r < 16; ++r) {
            float4* dst = (float4*)&xs[r][0];
            for (int i = tid; i < 320; i += 256) dst[i] = src[r * 320 + i];
        }
    }
    for (int i = tid; i < 2 * 16 * HROW; i += 256) {
        ((float*)h0s)[i] = 0.0f;
        ((float*)h1s)[i] = 0.0f;
    }

    // ---- weight B-fragments in registers (converted once) ----
    // B[k][col]: col = ug (gate g block), k = kk*32 + 8*kq + j; element =
    // W^T[k][gate] = W[gate][k] with gate = g*64 + ug.
    bf16x8 whh0hi[3][2], whh0lo[3][2];
    bf16x8 wih1hi[3][2], wih1lo[3][2];
    bf16x8 whh1hi[3][2], whh1lo[3][2];
#pragma unroll
    for (int g = 0; g < 3; ++g)
#pragma unroll
        for (int kk = 0; kk < 2; ++kk) {
            const int kbase = kk * 32 + 8 * kq;
            load_wfrag(w_hh0, g * 64 + ug, kbase, whh0hi[g][kk], whh0lo[g][kk]);
            load_wfrag(w_ih1, g * 64 + ug, kbase, wih1hi[g][kk], wih1lo[g][kk]);
            load_wfrag(w_hh1, g * 64 + ug, kbase, whh1hi[g][kk], whh1lo[g][kk]);
        }

    // per-lane layer-0 x-weights (unit ug) and biases
    float wxr[5], wxz[5], wxn[5];
#pragma unroll
    for (int d = 0; d < 5; ++d) {
        wxr[d] = w_ih0[(0 * 64 + ug) * 5 + d];
        wxz[d] = w_ih0[(1 * 64 + ug) * 5 + d];
        wxn[d] = w_ih0[(2 * 64 + ug) * 5 + d];
    }
    const float bR0  = b_ih0[ug] + b_hh0[ug];
    const float bZ0  = b_ih0[64 + ug] + b_hh0[64 + ug];
    const float bXN0 = b_ih0[128 + ug];
    const float bHN0 = b_hh0[128 + ug];
    const float bR1  = b_ih1[ug] + b_hh1[ug];
    const float bZ1  = b_ih1[64 + ug] + b_hh1[64 + ug];
    const float bXN1 = b_ih1[128 + ug];
    const float bHN1 = b_hh1[128 + ug];

    float h0_own[4] = {0.f, 0.f, 0.f, 0.f};  // h0[rbase+r][ug]
    float h1_own[4] = {0.f, 0.f, 0.f, 0.f};

    __syncthreads();

    int buf = 0;
    for (int t = 0; t < T_SZ; ++t) {
        // ================= Layer 0 =================
        bf16x8 a0hi[2], a0lo[2];
        {
            const float* h0row = &h0s[buf][u][0];
            load_afrag(h0row, 8 * kq,      a0hi[0], a0lo[0]);
            load_afrag(h0row, 32 + 8 * kq, a0hi[1], a0lo[1]);
        }
        f32x4 accR, accZ, accN;
        float xn0[4];
#pragma unroll
        for (int r = 0; r < 4; ++r) {
            const float* xp = &xs[rbase + r][t * 5];
            float vR = bR0, vZ = bZ0, vN = bXN0;
#pragma unroll
            for (int d = 0; d < 5; ++d) {
                float xv = xp[d];
                vR = fmaf(wxr[d], xv, vR);
                vZ = fmaf(wxz[d], xv, vZ);
                vN = fmaf(wxn[d], xv, vN);
            }
            accR[r] = vR; accZ[r] = vZ; xn0[r] = vN; accN[r] = bHN0;
        }
#pragma unroll
        for (int kk = 0; kk < 2; ++kk) {
            accR = MFMA16(a0hi[kk], whh0hi[0][kk], accR);
            accZ = MFMA16(a0hi[kk], whh0hi[1][kk], accZ);
            accN = MFMA16(a0hi[kk], whh0hi[2][kk], accN);
            accR = MFMA16(a0lo[kk], whh0hi[0][kk], accR);
            accZ = MFMA16(a0lo[kk], whh0hi[1][kk], accZ);
            accN = MFMA16(a0lo[kk], whh0hi[2][kk], accN);
            accR = MFMA16(a0hi[kk], whh0lo[0][kk], accR);
            accZ = MFMA16(a0hi[kk], whh0lo[1][kk], accZ);
            accN = MFMA16(a0hi[kk], whh0lo[2][kk], accN);
        }
#pragma unroll
        for (int r = 0; r < 4; ++r) {
            float rg = sigmoid_f(accR[r]);
            float zg = sigmoid_f(accZ[r]);
            float ng = tanh_f(fmaf(rg, accN[r], xn0[r]));
            float hv = (1.0f - zg) * ng + zg * h0_own[r];
            h0_own[r] = hv;
            h0s[buf ^ 1][rbase + r][ug] = hv;
        }
        __syncthreads();  // h0_new visible to all waves

        // ================= Layer 1 =================
        bf16x8 a1hi[2], a1lo[2], a2hi[2], a2lo[2];
        {
            const float* h0n = &h0s[buf ^ 1][u][0];
            const float* h1r = &h1s[buf][u][0];
            load_afrag(h0n, 8 * kq,      a1hi[0], a1lo[0]);
            load_afrag(h0n, 32 + 8 * kq, a1hi[1], a1lo[1]);
            load_afrag(h1r, 8 * kq,      a2hi[0], a2lo[0]);
            load_afrag(h1r, 32 + 8 * kq, a2hi[1], a2lo[1]);
        }
        f32x4 cR, cZ, cNx, cNh;
#pragma unroll
        for (int r = 0; r < 4; ++r) { cR[r] = bR1; cZ[r] = bZ1; cNx[r] = bXN1; cNh[r] = bHN1; }
#pragma unroll
        for (int kk = 0; kk < 2; ++kk) {
            // w_ih1 @ h0_new
            cR  = MFMA16(a1hi[kk], wih1hi[0][kk], cR);
            cZ  = MFMA16(a1hi[kk], wih1hi[1][kk], cZ);
            cNx = MFMA16(a1hi[kk], wih1hi[2][kk], cNx);
            cR  = MFMA16(a1lo[kk], wih1hi[0][kk], cR);
            cZ  = MFMA16(a1lo[kk], wih1hi[1][kk], cZ);
            cNx = MFMA16(a1lo[kk], wih1hi[2][kk], cNx);
            cR  = MFMA16(a1hi[kk], wih1lo[0][kk], cR);
            cZ  = MFMA16(a1hi[kk], wih1lo[1][kk], cZ);
            cNx = MFMA16(a1hi[kk], wih1lo[2][kk], cNx);
            // w_hh1 @ h1_old
            cR  = MFMA16(a2hi[kk], whh1hi[0][kk], cR);
            cZ  = MFMA16(a2hi[kk], whh1hi[1][kk], cZ);
            cNh = MFMA16(a2hi[kk], whh1hi[2][kk], cNh);
            cR  = MFMA16(a2lo[kk], whh1hi[0][kk], cR);
            cZ  = MFMA16(a2lo[kk], whh1hi[1][kk], cZ);
            cNh = MFMA16(a2lo[kk], whh1hi[2][kk], cNh);
            cR  = MFMA16(a2hi[kk], whh1lo[0][kk], cR);
            cZ  = MFMA16(a2hi[kk], whh1lo[1][kk], cZ);
            cNh = MFMA16(a2hi[kk], whh1lo[2][kk], cNh);
        }
#pragma unroll
        for (int r = 0; r < 4; ++r) {
            float rg = sigmoid_f(cR[r]);
            float zg = sigmoid_f(cZ[r]);
            float ng = tanh_f(fmaf(rg, cNh[r], cNx[r]));
            float hv = (1.0f - zg) * ng + zg * h1_own[r];
            h1_own[r] = hv;
            h1s[buf ^ 1][rbase + r][ug] = hv;
        }
        __syncthreads();  // h1_new visible; also protects next-step buffers
        buf ^= 1;
    }

    // ---- FC epilogue: out[row] = h1 . fc_w + fc_b ----
    if (tid < 16) {
        float s = fc_b[0];
#pragma unroll 1
        for (int uu = 0; uu < 64; ++uu) s = fmaf(fc_w[uu], h1s[buf][tid][uu], s);
        out[blockIdx.x * 16 + tid] = s;
    }
}

extern "C" void kernel_launch(void* const* d_in, const int* in_sizes, int n_in,
                              void* d_out, int out_size, void* d_ws, size_t ws_size,
                              hipStream_t stream) {
    const float* x     = (const float*)d_in[0];
    const float* w_ih0 = (const float*)d_in[1];
    const float* w_hh0 = (const float*)d_in[2];
    const float* b_ih0 = (const float*)d_in[3];
    const float* b_hh0 = (const float*)d_in[4];
    const float* w_ih1 = (const float*)d_in[5];
    const float* w_hh1 = (const float*)d_in[6];
    const float* b_ih1 = (const float*)d_in[7];
    const float* b_hh1 = (const float*)d_in[8];
    const float* fc_w  = (const float*)d_in[9];
    const float* fc_b  = (const float*)d_in[10];
    float* out = (float*)d_out;

    gru2_mfma<<<dim3(256), dim3(256), 0, stream>>>(x, w_ih0, w_hh0, b_ih0, b_hh0,
                                                   w_ih1, w_hh1, b_ih1, b_hh1,
                                                   fc_w, fc_b, out);
}

// Round 6
// 339.547 us; speedup vs baseline: 4.4783x; 1.2455x over previous
//
#include <hip/hip_runtime.h>
#include <hip/hip_bf16.h>

// GRU2 + FC, MFMA version, r4 (second resubmit after repeated infra failures).
// vs r3: (1) h stored in LDS as bf16 hi/lo, converted ONCE by the producing
// lane (kills ~290 VALU cvt ops/wave/step); (2) ONE barrier per timestep
// (double-buffer analysis: all RAW/WAR deps cross barrier(t) placed between
// L0 and L1); (3) L1 accumulators split per source matrix (chain 12 -> 6).
// Layout (verified m89): D col=lane&15, row=(lane>>4)*4+reg; A row=lane&15,
// k=kk*32+8*(lane>>4)+j; B col=lane&15, same k. fp32 accuracy via 3-term
// bf16 hi/lo compensation: Ahi*Bhi + Alo*Bhi + Ahi*Blo.

typedef __attribute__((ext_vector_type(8))) __bf16 bf16x8;
typedef __attribute__((ext_vector_type(4))) float f32x4;

#define MFMA16(a, b, c) __builtin_amdgcn_mfma_f32_16x16x32_bf16(a, b, c, 0, 0, 0)

#define T_SZ 256
#define XROW 1284  // 1280 + 4 pad
#define HB   72    // bf16 row stride: 144B -> b128 reads spread 8 words/bank

__device__ __forceinline__ float sigmoid_f(float v) {
    float e = __expf(-v);
    return __builtin_amdgcn_rcpf(1.0f + e);
}
__device__ __forceinline__ float tanh_f(float v) {
    float e = __expf(-2.0f * v);
    return (1.0f - e) * __builtin_amdgcn_rcpf(1.0f + e);
}

__device__ __forceinline__ void cvt_hilo8(const float* v, bf16x8& hi, bf16x8& lo) {
#pragma unroll
    for (int j = 0; j < 8; ++j) {
        __bf16 h = (__bf16)v[j];
        hi[j] = h;
        lo[j] = (__bf16)(v[j] - (float)h);
    }
}

__device__ __forceinline__ void load_wfrag(const float* __restrict__ W, int grow,
                                           int kbase, bf16x8& hi, bf16x8& lo) {
    float v[8];
#pragma unroll
    for (int j = 0; j < 8; ++j) v[j] = W[grow * 64 + kbase + j];
    cvt_hilo8(v, hi, lo);
}

__global__ __launch_bounds__(256, 1)
void gru2_mfma2(const float* __restrict__ x,
                const float* __restrict__ w_ih0, const float* __restrict__ w_hh0,
                const float* __restrict__ b_ih0, const float* __restrict__ b_hh0,
                const float* __restrict__ w_ih1, const float* __restrict__ w_hh1,
                const float* __restrict__ b_ih1, const float* __restrict__ b_hh1,
                const float* __restrict__ fc_w, const float* __restrict__ fc_b,
                float* __restrict__ out)
{
    __shared__ __align__(16) float xs[16][XROW];        // ~82 KB
    __shared__ __align__(16) __bf16 h0hi[2][16][HB];    // 4.5 KB each
    __shared__ __align__(16) __bf16 h0lo[2][16][HB];
    __shared__ __align__(16) __bf16 h1hi[2][16][HB];
    __shared__ __align__(16) __bf16 h1lo[2][16][HB];

    const int tid  = threadIdx.x;
    const int lane = tid & 63;
    const int wave = tid >> 6;
    const int u    = lane & 15;       // A-row / unit offset in wave's chunk
    const int kq   = lane >> 4;       // k-quadrant / D row-group
    const int ug   = wave * 16 + u;   // global gate-unit 0..63
    const int rbase = 4 * kq;         // lane's batch-row base

    // ---- stage x slice, padded rows ----
    {
        const float4* src = (const float4*)(x + (size_t)blockIdx.x * 16 * 1280);
#pragma unroll 1
        for (int r = 0; r < 16; ++r) {
            float4* dst = (float4*)&xs[r][0];
            for (int i = tid; i < 320; i += 256) dst[i] = src[r * 320 + i];
        }
    }
    for (int i = tid; i < 2 * 16 * HB; i += 256) {
        ((__bf16*)h0hi)[i] = (__bf16)0.0f;
        ((__bf16*)h0lo)[i] = (__bf16)0.0f;
        ((__bf16*)h1hi)[i] = (__bf16)0.0f;
        ((__bf16*)h1lo)[i] = (__bf16)0.0f;
    }

    // ---- weight B-fragments in registers ----
    bf16x8 whh0hi[3][2], whh0lo[3][2];
    bf16x8 wih1hi[3][2], wih1lo[3][2];
    bf16x8 whh1hi[3][2], whh1lo[3][2];
#pragma unroll
    for (int g = 0; g < 3; ++g)
#pragma unroll
        for (int kk = 0; kk < 2; ++kk) {
            const int kbase = kk * 32 + 8 * kq;
            load_wfrag(w_hh0, g * 64 + ug, kbase, whh0hi[g][kk], whh0lo[g][kk]);
            load_wfrag(w_ih1, g * 64 + ug, kbase, wih1hi[g][kk], wih1lo[g][kk]);
            load_wfrag(w_hh1, g * 64 + ug, kbase, whh1hi[g][kk], whh1lo[g][kk]);
        }

    float wxr[5], wxz[5], wxn[5];
#pragma unroll
    for (int d = 0; d < 5; ++d) {
        wxr[d] = w_ih0[(0 * 64 + ug) * 5 + d];
        wxz[d] = w_ih0[(1 * 64 + ug) * 5 + d];
        wxn[d] = w_ih0[(2 * 64 + ug) * 5 + d];
    }
    const float bR0  = b_ih0[ug] + b_hh0[ug];
    const float bZ0  = b_ih0[64 + ug] + b_hh0[64 + ug];
    const float bXN0 = b_ih0[128 + ug];
    const float bHN0 = b_hh0[128 + ug];
    const float bR1  = b_ih1[ug] + b_hh1[ug];
    const float bZ1  = b_ih1[64 + ug] + b_hh1[64 + ug];
    const float bXN1 = b_ih1[128 + ug];
    const float bHN1 = b_hh1[128 + ug];

    float h0_own[4] = {0.f, 0.f, 0.f, 0.f};
    float h1_own[4] = {0.f, 0.f, 0.f, 0.f};

    __syncthreads();

    for (int t = 0; t < T_SZ; ++t) {
        const int p = t & 1;
        // ================= Layer 0 (pre-barrier) =================
        bf16x8 a0h[2], a0l[2];
        a0h[0] = *(const bf16x8*)&h0hi[p][u][8 * kq];
        a0h[1] = *(const bf16x8*)&h0hi[p][u][32 + 8 * kq];
        a0l[0] = *(const bf16x8*)&h0lo[p][u][8 * kq];
        a0l[1] = *(const bf16x8*)&h0lo[p][u][32 + 8 * kq];

        f32x4 accR, accZ, accN;
        float xn0[4];
#pragma unroll
        for (int r = 0; r < 4; ++r) {
            const float* xp = &xs[rbase + r][t * 5];
            float vR = bR0, vZ = bZ0, vN = bXN0;
#pragma unroll
            for (int d = 0; d < 5; ++d) {
                float xv = xp[d];
                vR = fmaf(wxr[d], xv, vR);
                vZ = fmaf(wxz[d], xv, vZ);
                vN = fmaf(wxn[d], xv, vN);
            }
            accR[r] = vR; accZ[r] = vZ; xn0[r] = vN; accN[r] = bHN0;
        }
#pragma unroll
        for (int kk = 0; kk < 2; ++kk) {
            accR = MFMA16(a0h[kk], whh0hi[0][kk], accR);
            accZ = MFMA16(a0h[kk], whh0hi[1][kk], accZ);
            accN = MFMA16(a0h[kk], whh0hi[2][kk], accN);
            accR = MFMA16(a0l[kk], whh0hi[0][kk], accR);
            accZ = MFMA16(a0l[kk], whh0hi[1][kk], accZ);
            accN = MFMA16(a0l[kk], whh0hi[2][kk], accN);
            accR = MFMA16(a0h[kk], whh0lo[0][kk], accR);
            accZ = MFMA16(a0h[kk], whh0lo[1][kk], accZ);
            accN = MFMA16(a0h[kk], whh0lo[2][kk], accN);
        }
#pragma unroll
        for (int r = 0; r < 4; ++r) {
            float rg = sigmoid_f(accR[r]);
            float zg = sigmoid_f(accZ[r]);
            float ng = tanh_f(fmaf(rg, accN[r], xn0[r]));
            float hv = (1.0f - zg) * ng + zg * h0_own[r];
            h0_own[r] = hv;
            __bf16 hi = (__bf16)hv;
            __bf16 lo = (__bf16)(hv - (float)hi);
            h0hi[p ^ 1][rbase + r][ug] = hi;
            h0lo[p ^ 1][rbase + r][ug] = lo;
        }
        __syncthreads();  // the ONLY barrier per step
        // ================= Layer 1 (post-barrier) =================
        bf16x8 a1h[2], a1l[2], a2h[2], a2l[2];
        a1h[0] = *(const bf16x8*)&h0hi[p ^ 1][u][8 * kq];
        a1h[1] = *(const bf16x8*)&h0hi[p ^ 1][u][32 + 8 * kq];
        a1l[0] = *(const bf16x8*)&h0lo[p ^ 1][u][8 * kq];
        a1l[1] = *(const bf16x8*)&h0lo[p ^ 1][u][32 + 8 * kq];
        a2h[0] = *(const bf16x8*)&h1hi[p][u][8 * kq];
        a2h[1] = *(const bf16x8*)&h1hi[p][u][32 + 8 * kq];
        a2l[0] = *(const bf16x8*)&h1lo[p][u][8 * kq];
        a2l[1] = *(const bf16x8*)&h1lo[p][u][32 + 8 * kq];

        f32x4 cRa, cRb, cZa, cZb, cNx, cNh;
#pragma unroll
        for (int r = 0; r < 4; ++r) {
            cRa[r] = bR1;  cRb[r] = 0.f;
            cZa[r] = bZ1;  cZb[r] = 0.f;
            cNx[r] = bXN1; cNh[r] = bHN1;
        }
#pragma unroll
        for (int kk = 0; kk < 2; ++kk) {
            // w_ih1 @ h0_new  (chains a)
            cRa = MFMA16(a1h[kk], wih1hi[0][kk], cRa);
            cZa = MFMA16(a1h[kk], wih1hi[1][kk], cZa);
            cNx = MFMA16(a1h[kk], wih1hi[2][kk], cNx);
            cRa = MFMA16(a1l[kk], wih1hi[0][kk], cRa);
            cZa = MFMA16(a1l[kk], wih1hi[1][kk], cZa);
            cNx = MFMA16(a1l[kk], wih1hi[2][kk], cNx);
            cRa = MFMA16(a1h[kk], wih1lo[0][kk], cRa);
            cZa = MFMA16(a1h[kk], wih1lo[1][kk], cZa);
            cNx = MFMA16(a1h[kk], wih1lo[2][kk], cNx);
            // w_hh1 @ h1_old  (chains b)
            cRb = MFMA16(a2h[kk], whh1hi[0][kk], cRb);
            cZb = MFMA16(a2h[kk], whh1hi[1][kk], cZb);
            cNh = MFMA16(a2h[kk], whh1hi[2][kk], cNh);
            cRb = MFMA16(a2l[kk], whh1hi[0][kk], cRb);
            cZb = MFMA16(a2l[kk], whh1hi[1][kk], cZb);
            cNh = MFMA16(a2l[kk], whh1hi[2][kk], cNh);
            cRb = MFMA16(a2h[kk], whh1lo[0][kk], cRb);
            cZb = MFMA16(a2h[kk], whh1lo[1][kk], cZb);
            cNh = MFMA16(a2h[kk], whh1lo[2][kk], cNh);
        }
#pragma unroll
        for (int r = 0; r < 4; ++r) {
            float rg = sigmoid_f(cRa[r] + cRb[r]);
            float zg = sigmoid_f(cZa[r] + cZb[r]);
            float ng = tanh_f(fmaf(rg, cNh[r], cNx[r]));
            float hv = (1.0f - zg) * ng + zg * h1_own[r];
            h1_own[r] = hv;
            __bf16 hi = (__bf16)hv;
            __bf16 lo = (__bf16)(hv - (float)hi);
            h1hi[p ^ 1][rbase + r][ug] = hi;
            h1lo[p ^ 1][rbase + r][ug] = lo;
        }
        // no trailing barrier: L0(t+1) touches only h0s[p], disjoint from
        // L1(t)'s h0s[p^1]/h1s[p] reads; all other deps cross barrier(t+1).
    }
    __syncthreads();

    // ---- FC epilogue: final h1 is in buffer (255&1)^1 = 0 ----
    if (tid < 16) {
        float s = fc_b[0];
#pragma unroll 1
        for (int uu = 0; uu < 64; ++uu)
            s = fmaf(fc_w[uu], (float)h1hi[0][tid][uu] + (float)h1lo[0][tid][uu], s);
        out[blockIdx.x * 16 + tid] = s;
    }
}

extern "C" void kernel_launch(void* const* d_in, const int* in_sizes, int n_in,
                              void* d_out, int out_size, void* d_ws, size_t ws_size,
                              hipStream_t stream) {
    const float* x     = (const float*)d_in[0];
    const float* w_ih0 = (const float*)d_in[1];
    const float* w_hh0 = (const float*)d_in[2];
    const float* b_ih0 = (const float*)d_in[3];
    const float* b_hh0 = (const float*)d_in[4];
    const float* w_ih1 = (const float*)d_in[5];
    const float* w_hh1 = (const float*)d_in[6];
    const float* b_ih1 = (const float*)d_in[7];
    const float* b_hh1 = (const float*)d_in[8];
    const float* fc_w  = (const float*)d_in[9];
    const float* fc_b  = (const float*)d_in[10];
    float* out = (float*)d_out;

    gru2_mfma2<<<dim3(256), dim3(256), 0, stream>>>(x, w_ih0, w_hh0, b_ih0, b_hh0,
                                                    w_ih1, w_hh1, b_ih1, b_hh1,
                                                    fc_w, fc_b, out);
}

// Round 7
// 276.373 us; speedup vs baseline: 5.5020x; 1.2286x over previous
//
#include <hip/hip_runtime.h>
#include <hip/hip_bf16.h>

// GRU2 + FC, r5: layer-specialized wave pipeline.
// 256 blocks x 512 threads. Waves 0-3: layer 0 step i; waves 4-7: layer 1
// step i-1 (1-step skew). Each group runs its own t-loop with one matched
// __syncthreads per iteration (257 barriers each side) -> 2 waves/SIMD, each
// hiding the other's latency. h0/h1 double-buffered bf16 hi/lo in LDS
// (producer-side conversion). Slot math: h(j) -> slot j&1; all RAW deps
// cross exactly one barrier, WAR pairs are read-pre-barrier/write-post.
// Layouts (m89-verified): D col=lane&15, row=(lane>>4)*4+reg; A row=lane&15,
// k=kk*32+8*(lane>>4)+j; B col=lane&15 same k. fp32 accuracy via 3-term
// bf16 hi/lo compensation (Ahi*Bhi + Alo*Bhi + Ahi*Blo).

typedef __attribute__((ext_vector_type(8))) __bf16 bf16x8;
typedef __attribute__((ext_vector_type(4))) float f32x4;

#define MFMA16(a, b, c) __builtin_amdgcn_mfma_f32_16x16x32_bf16(a, b, c, 0, 0, 0)

#define T_SZ 256
#define XROW 1284  // 1280 + 4 pad
#define HB   72    // bf16 row stride: 144B

__device__ __forceinline__ float sigmoid_f(float v) {
    float e = __expf(-v);
    return __builtin_amdgcn_rcpf(1.0f + e);
}
__device__ __forceinline__ float tanh_f(float v) {
    float e = __expf(-2.0f * v);
    return (1.0f - e) * __builtin_amdgcn_rcpf(1.0f + e);
}

__device__ __forceinline__ void cvt_hilo8(const float* v, bf16x8& hi, bf16x8& lo) {
#pragma unroll
    for (int j = 0; j < 8; ++j) {
        __bf16 h = (__bf16)v[j];
        hi[j] = h;
        lo[j] = (__bf16)(v[j] - (float)h);
    }
}

__device__ __forceinline__ void load_wfrag(const float* __restrict__ W, int grow,
                                           int kbase, bf16x8& hi, bf16x8& lo) {
    float v[8];
#pragma unroll
    for (int j = 0; j < 8; ++j) v[j] = W[grow * 64 + kbase + j];
    cvt_hilo8(v, hi, lo);
}

__global__ __launch_bounds__(512, 2)
void gru2_pipe(const float* __restrict__ x,
               const float* __restrict__ w_ih0, const float* __restrict__ w_hh0,
               const float* __restrict__ b_ih0, const float* __restrict__ b_hh0,
               const float* __restrict__ w_ih1, const float* __restrict__ w_hh1,
               const float* __restrict__ b_ih1, const float* __restrict__ b_hh1,
               const float* __restrict__ fc_w, const float* __restrict__ fc_b,
               float* __restrict__ out)
{
    __shared__ __align__(16) float xs[16][XROW];        // ~82 KB
    __shared__ __align__(16) __bf16 h0hi[2][16][HB];    // 4.5 KB each
    __shared__ __align__(16) __bf16 h0lo[2][16][HB];
    __shared__ __align__(16) __bf16 h1hi[2][16][HB];
    __shared__ __align__(16) __bf16 h1lo[2][16][HB];

    const int tid  = threadIdx.x;
    const int lane = tid & 63;
    const int wave = tid >> 6;        // 0..7
    const int u    = lane & 15;
    const int kq   = lane >> 4;
    const int wl   = wave & 3;        // wave index within layer group
    const int ug   = wl * 16 + u;     // gate-unit 0..63
    const int rbase = 4 * kq;

    // ---- stage x slice (coalesced), padded rows ----
    {
        const float4* src = (const float4*)(x + (size_t)blockIdx.x * 16 * 1280);
        for (int idx = tid; idx < 16 * 320; idx += 512) {
            int r = idx / 320, i4 = idx - r * 320;
            ((float4*)&xs[r][0])[i4] = src[idx];
        }
    }
    for (int idx = tid; idx < 2 * 16 * HB; idx += 512) {
        ((__bf16*)h0hi)[idx] = (__bf16)0.0f;
        ((__bf16*)h0lo)[idx] = (__bf16)0.0f;
        ((__bf16*)h1hi)[idx] = (__bf16)0.0f;
        ((__bf16*)h1lo)[idx] = (__bf16)0.0f;
    }
    __syncthreads();

    if (wave < 4) {
        // =================== Layer-0 group ===================
        bf16x8 whh0hi[3][2], whh0lo[3][2];
#pragma unroll
        for (int g = 0; g < 3; ++g)
#pragma unroll
            for (int kk = 0; kk < 2; ++kk)
                load_wfrag(w_hh0, g * 64 + ug, kk * 32 + 8 * kq,
                           whh0hi[g][kk], whh0lo[g][kk]);
        float wxr[5], wxz[5], wxn[5];
#pragma unroll
        for (int d = 0; d < 5; ++d) {
            wxr[d] = w_ih0[(0 * 64 + ug) * 5 + d];
            wxz[d] = w_ih0[(1 * 64 + ug) * 5 + d];
            wxn[d] = w_ih0[(2 * 64 + ug) * 5 + d];
        }
        const float bR0  = b_ih0[ug] + b_hh0[ug];
        const float bZ0  = b_ih0[64 + ug] + b_hh0[64 + ug];
        const float bXN0 = b_ih0[128 + ug];
        const float bHN0 = b_hh0[128 + ug];
        float h0_own[4] = {0.f, 0.f, 0.f, 0.f};

        for (int i = 0; i <= T_SZ; ++i) {
            if (i < T_SZ) {
                const int ps = i & 1;      // write slot: h0(i)
                const int pr = ps ^ 1;     // read slot:  h0(i-1)
                bf16x8 a0h[2], a0l[2];
                a0h[0] = *(const bf16x8*)&h0hi[pr][u][8 * kq];
                a0h[1] = *(const bf16x8*)&h0hi[pr][u][32 + 8 * kq];
                a0l[0] = *(const bf16x8*)&h0lo[pr][u][8 * kq];
                a0l[1] = *(const bf16x8*)&h0lo[pr][u][32 + 8 * kq];

                f32x4 accR, accZ, accN;
                float xn0[4];
#pragma unroll
                for (int r = 0; r < 4; ++r) {
                    const float* xp = &xs[rbase + r][i * 5];
                    float vR = bR0, vZ = bZ0, vN = bXN0;
#pragma unroll
                    for (int d = 0; d < 5; ++d) {
                        float xv = xp[d];
                        vR = fmaf(wxr[d], xv, vR);
                        vZ = fmaf(wxz[d], xv, vZ);
                        vN = fmaf(wxn[d], xv, vN);
                    }
                    accR[r] = vR; accZ[r] = vZ; xn0[r] = vN; accN[r] = bHN0;
                }
#pragma unroll
                for (int kk = 0; kk < 2; ++kk) {
                    accR = MFMA16(a0h[kk], whh0hi[0][kk], accR);
                    accZ = MFMA16(a0h[kk], whh0hi[1][kk], accZ);
                    accN = MFMA16(a0h[kk], whh0hi[2][kk], accN);
                    accR = MFMA16(a0l[kk], whh0hi[0][kk], accR);
                    accZ = MFMA16(a0l[kk], whh0hi[1][kk], accZ);
                    accN = MFMA16(a0l[kk], whh0hi[2][kk], accN);
                    accR = MFMA16(a0h[kk], whh0lo[0][kk], accR);
                    accZ = MFMA16(a0h[kk], whh0lo[1][kk], accZ);
                    accN = MFMA16(a0h[kk], whh0lo[2][kk], accN);
                }
#pragma unroll
                for (int r = 0; r < 4; ++r) {
                    float rg = sigmoid_f(accR[r]);
                    float zg = sigmoid_f(accZ[r]);
                    float ng = tanh_f(fmaf(rg, accN[r], xn0[r]));
                    float hv = (1.0f - zg) * ng + zg * h0_own[r];
                    h0_own[r] = hv;
                    __bf16 hi = (__bf16)hv;
                    __bf16 lo = (__bf16)(hv - (float)hi);
                    h0hi[ps][rbase + r][ug] = hi;
                    h0lo[ps][rbase + r][ug] = lo;
                }
            }
            __syncthreads();
        }
    } else {
        // =================== Layer-1 group ===================
        bf16x8 wih1hi[3][2], wih1lo[3][2];
        bf16x8 whh1hi[3][2], whh1lo[3][2];
#pragma unroll
        for (int g = 0; g < 3; ++g)
#pragma unroll
            for (int kk = 0; kk < 2; ++kk) {
                const int kbase = kk * 32 + 8 * kq;
                load_wfrag(w_ih1, g * 64 + ug, kbase, wih1hi[g][kk], wih1lo[g][kk]);
                load_wfrag(w_hh1, g * 64 + ug, kbase, whh1hi[g][kk], whh1lo[g][kk]);
            }
        const float bR1  = b_ih1[ug] + b_hh1[ug];
        const float bZ1  = b_ih1[64 + ug] + b_hh1[64 + ug];
        const float bXN1 = b_ih1[128 + ug];
        const float bHN1 = b_hh1[128 + ug];
        float h1_own[4] = {0.f, 0.f, 0.f, 0.f};

        for (int i = 0; i <= T_SZ; ++i) {
            if (i >= 1) {
                const int t  = i - 1;
                const int s0 = t & 1;       // h0(t) slot; h1(t) write slot
                const int s1 = s0 ^ 1;      // h1(t-1) slot
                bf16x8 a1h[2], a1l[2], a2h[2], a2l[2];
                a1h[0] = *(const bf16x8*)&h0hi[s0][u][8 * kq];
                a1h[1] = *(const bf16x8*)&h0hi[s0][u][32 + 8 * kq];
                a1l[0] = *(const bf16x8*)&h0lo[s0][u][8 * kq];
                a1l[1] = *(const bf16x8*)&h0lo[s0][u][32 + 8 * kq];
                a2h[0] = *(const bf16x8*)&h1hi[s1][u][8 * kq];
                a2h[1] = *(const bf16x8*)&h1hi[s1][u][32 + 8 * kq];
                a2l[0] = *(const bf16x8*)&h1lo[s1][u][8 * kq];
                a2l[1] = *(const bf16x8*)&h1lo[s1][u][32 + 8 * kq];

                f32x4 cRa, cRb, cZa, cZb, cNx, cNh;
#pragma unroll
                for (int r = 0; r < 4; ++r) {
                    cRa[r] = bR1;  cRb[r] = 0.f;
                    cZa[r] = bZ1;  cZb[r] = 0.f;
                    cNx[r] = bXN1; cNh[r] = bHN1;
                }
#pragma unroll
                for (int kk = 0; kk < 2; ++kk) {
                    cRa = MFMA16(a1h[kk], wih1hi[0][kk], cRa);
                    cZa = MFMA16(a1h[kk], wih1hi[1][kk], cZa);
                    cNx = MFMA16(a1h[kk], wih1hi[2][kk], cNx);
                    cRa = MFMA16(a1l[kk], wih1hi[0][kk], cRa);
                    cZa = MFMA16(a1l[kk], wih1hi[1][kk], cZa);
                    cNx = MFMA16(a1l[kk], wih1hi[2][kk], cNx);
                    cRa = MFMA16(a1h[kk], wih1lo[0][kk], cRa);
                    cZa = MFMA16(a1h[kk], wih1lo[1][kk], cZa);
                    cNx = MFMA16(a1h[kk], wih1lo[2][kk], cNx);
                    cRb = MFMA16(a2h[kk], whh1hi[0][kk], cRb);
                    cZb = MFMA16(a2h[kk], whh1hi[1][kk], cZb);
                    cNh = MFMA16(a2h[kk], whh1hi[2][kk], cNh);
                    cRb = MFMA16(a2l[kk], whh1hi[0][kk], cRb);
                    cZb = MFMA16(a2l[kk], whh1hi[1][kk], cZb);
                    cNh = MFMA16(a2l[kk], whh1hi[2][kk], cNh);
                    cRb = MFMA16(a2h[kk], whh1lo[0][kk], cRb);
                    cZb = MFMA16(a2h[kk], whh1lo[1][kk], cZb);
                    cNh = MFMA16(a2h[kk], whh1lo[2][kk], cNh);
                }
#pragma unroll
                for (int r = 0; r < 4; ++r) {
                    float rg = sigmoid_f(cRa[r] + cRb[r]);
                    float zg = sigmoid_f(cZa[r] + cZb[r]);
                    float ng = tanh_f(fmaf(rg, cNh[r], cNx[r]));
                    float hv = (1.0f - zg) * ng + zg * h1_own[r];
                    h1_own[r] = hv;
                    __bf16 hi = (__bf16)hv;
                    __bf16 lo = (__bf16)(hv - (float)hi);
                    h1hi[s0][rbase + r][ug] = hi;
                    h1lo[s0][rbase + r][ug] = lo;
                }
            }
            __syncthreads();
        }
    }

    // ---- FC epilogue: h1(255) lives in slot 255&1 = 1 ----
    if (tid < 16) {
        float s = fc_b[0];
#pragma unroll 1
        for (int uu = 0; uu < 64; ++uu)
            s = fmaf(fc_w[uu], (float)h1hi[1][tid][uu] + (float)h1lo[1][tid][uu], s);
        out[blockIdx.x * 16 + tid] = s;
    }
}

extern "C" void kernel_launch(void* const* d_in, const int* in_sizes, int n_in,
                              void* d_out, int out_size, void* d_ws, size_t ws_size,
                              hipStream_t stream) {
    const float* x     = (const float*)d_in[0];
    const float* w_ih0 = (const float*)d_in[1];
    const float* w_hh0 = (const float*)d_in[2];
    const float* b_ih0 = (const float*)d_in[3];
    const float* b_hh0 = (const float*)d_in[4];
    const float* w_ih1 = (const float*)d_in[5];
    const float* w_hh1 = (const float*)d_in[6];
    const float* b_ih1 = (const float*)d_in[7];
    const float* b_hh1 = (const float*)d_in[8];
    const float* fc_w  = (const float*)d_in[9];
    const float* fc_b  = (const float*)d_in[10];
    float* out = (float*)d_out;

    gru2_pipe<<<dim3(256), dim3(512), 0, stream>>>(x, w_ih0, w_hh0, b_ih0, b_hh0,
                                                   w_ih1, w_hh1, b_ih1, b_hh1,
                                                   fc_w, fc_b, out);
}